// Round 1
// 399.328 us; speedup vs baseline: 1.1316x; 1.1316x over previous
//
#include <hip/hip_runtime.h>
#include <math.h>

// Problem constants (B=4, T=4096, D_MODEL=1024, H=16, D_HEAD=64, MEM=256)
constexpr int B_  = 4;
constexpr int T_  = 4096;
constexpr int DM_ = 1024;
constexpr int H_  = 16;
constexpr int S_  = 256;
constexpr int BT_ = B_ * T_;                    // 16384
constexpr int NTILE_ = T_ / 64;                 // 64 token-tiles per (b,h)
constexpr size_t QELEMS = (size_t)BT_ * DM_;    // 16,777,216

typedef _Float16 v8h __attribute__((ext_vector_type(8)));
typedef _Float16 v4h __attribute__((ext_vector_type(4)));
typedef float    v4f __attribute__((ext_vector_type(4)));

// Static device scratch; every element rewritten each call before any read.
__device__ _Float16 g_AH[QELEMS];        // fp16 x, later rewritten as fp16 out_pre*512
__device__ _Float16 g_QH[QELEMS];        // fp16 Q projection
__device__ _Float16 g_WqH[DM_ * DM_];    // fp16 Wq
__device__ _Float16 g_WoH[DM_ * DM_];    // fp16 Wo
__device__ _Float16 g_MkH[H_ * S_ * 64]; // fp16 Mk (row-major [h][s][d])
__device__ _Float16 g_MvT[H_ * 64 * S_]; // fp16 Mv transposed: [h][d][s]
__device__ _Float16 g_Mv2[(size_t)B_ * H_ * 64 * S_]; // fp16 cinv-scaled MvT: [b][h][d][s]
__device__ _Float16 g_P[(size_t)B_ * H_ * T_ * S_];   // fp16 row-softmaxed P: [bh][tile][t64][s256]
__device__ float    g_cpart[(size_t)B_ * H_ * NTILE_ * S_];
__device__ float    g_colsum_inv[B_ * H_ * S_];

// ---------------------------------------------------------------------------
// fp32 -> fp16 conversion, 8 elems/thread.
// ---------------------------------------------------------------------------
__global__ __launch_bounds__(256) void cvt_h(const float* __restrict__ src,
                                             _Float16* __restrict__ dst) {
  const size_t i = (size_t)blockIdx.x * 256 + threadIdx.x;
  const float4* s = (const float4*)src;
  float4 a = s[2 * i], b = s[2 * i + 1];
  v8h o;
  o[0] = (_Float16)a.x; o[1] = (_Float16)a.y; o[2] = (_Float16)a.z; o[3] = (_Float16)a.w;
  o[4] = (_Float16)b.x; o[5] = (_Float16)b.y; o[6] = (_Float16)b.z; o[7] = (_Float16)b.w;
  *(v8h*)&dst[8 * i] = o;
}

// ---------------------------------------------------------------------------
// Mv fp32 [h][s][d] -> fp16 transposed [h][d][s]. 262144 elems, 1024 blocks.
// ---------------------------------------------------------------------------
__global__ __launch_bounds__(256) void transpose_mv(const float* __restrict__ Mv) {
  const int idx = blockIdx.x * 256 + threadIdx.x;
  const int h = idx >> 14, rem = idx & 16383;
  const int s = rem >> 6, d = rem & 63;
  g_MvT[h * 16384 + d * 256 + s] = (_Float16)Mv[idx];
}

// ---------------------------------------------------------------------------
// MFMA GEMM body: C = scale * A @ W^T, fp16 in. 128x128 tile, BK=64,
// 256 thr = 4 waves (2x2), each wave 4x4 of 16x16x32 MFMAs.
// ---------------------------------------------------------------------------
template <typename OUT_T>
__device__ __forceinline__ void gemm_body(const _Float16* __restrict__ Ah,
                                          const _Float16* __restrict__ Wh,
                                          OUT_T* __restrict__ C, float scale) {
  __shared__ _Float16 As[128][72];
  __shared__ _Float16 Bs[128][72];
  const int tid  = threadIdx.x;
  const int m0   = blockIdx.x * 128;
  const int n0   = blockIdx.y * 128;
  const int wid  = tid >> 6;
  const int wm   = wid & 1;
  const int wn   = wid >> 1;
  const int lane = tid & 63;
  const int l15  = lane & 15;
  const int quad = lane >> 4;

  v4f acc[4][4] = {};

  for (int k0 = 0; k0 < 1024; k0 += 64) {
#pragma unroll
    for (int i = 0; i < 4; ++i) {
      int c  = i * 256 + tid;
      int r  = c >> 3;
      int ch = (c & 7) * 8;
      *(v8h*)&As[r][ch] = *(const v8h*)&Ah[(size_t)(m0 + r) * 1024 + k0 + ch];
      *(v8h*)&Bs[r][ch] = *(const v8h*)&Wh[(size_t)(n0 + r) * 1024 + k0 + ch];
    }
    __syncthreads();
#pragma unroll
    for (int kk = 0; kk < 2; ++kk) {
      v8h af[4], bf[4];
#pragma unroll
      for (int i = 0; i < 4; ++i)
        af[i] = *(const v8h*)&As[wm * 64 + i * 16 + l15][kk * 32 + quad * 8];
#pragma unroll
      for (int j = 0; j < 4; ++j)
        bf[j] = *(const v8h*)&Bs[wn * 64 + j * 16 + l15][kk * 32 + quad * 8];
#pragma unroll
      for (int i = 0; i < 4; ++i)
#pragma unroll
        for (int j = 0; j < 4; ++j)
          acc[i][j] = __builtin_amdgcn_mfma_f32_16x16x32_f16(af[i], bf[j], acc[i][j], 0, 0, 0);
    }
    __syncthreads();
  }
#pragma unroll
  for (int i = 0; i < 4; ++i) {
    const size_t mrow = (size_t)(m0 + wm * 64 + i * 16 + quad * 4);
#pragma unroll
    for (int j = 0; j < 4; ++j) {
      const int ncol = n0 + wn * 64 + j * 16 + l15;
#pragma unroll
      for (int r = 0; r < 4; ++r)
        C[(mrow + r) * 1024 + ncol] = (OUT_T)(acc[i][j][r] * scale);
    }
  }
}

__global__ __launch_bounds__(256) void gemm_q16(const _Float16* __restrict__ Wq) {
  gemm_body<_Float16>(g_AH, Wq, g_QH, 1.0f);
}
__global__ __launch_bounds__(256) void gemm_o(const _Float16* __restrict__ Wo,
                                              float* __restrict__ out) {
  gemm_body<float>(g_AH, Wo, out, 1.0f / 512.0f);
}

// ---------------------------------------------------------------------------
// Pass 1 (single QK+softmax): per (bh, 64-token tile):
//   - stage Mk[h] (32 KB) into LDS, XOR-swizzled 16B chunks (conflict-free
//     ds_read_b128 B-frags; row stride 128 B would be a 16-way conflict)
//   - QK^T via MFMA from LDS, row-softmax in registers
//   - column-sum partials -> g_cpart
//   - transpose P via LDS (aliases the Mk stage, dead after QK) and store
//     row-softmaxed P (NO cinv yet) as fp16 to g_P, v8h-coalesced [t][s].
// ---------------------------------------------------------------------------
__global__ __launch_bounds__(256) void attn_p1() {
  __shared__ __align__(16) _Float16 Psh[64][272];   // 34816 B; bytes [0,32768) alias Mk stage
  __shared__ float csum_sh[4][256];
  const int tid  = threadIdx.x;
  const int bh   = blockIdx.x;
  const int b    = bh >> 4, h = bh & 15;
  const int tile = blockIdx.y;
  const int t0   = tile * 64;
  const int wid  = tid >> 6;
  const int lane = tid & 63;
  const int l15  = lane & 15;
  const int quad = lane >> 4;
  char* MkS = (char*)&Psh[0][0];

  // Q fragments (HBM, cold) — issue first so latency overlaps Mk staging
  const _Float16* qrow = &g_QH[(size_t)(b * T_ + t0 + wid * 16 + l15) * 1024 + h * 64];
  v8h af0 = *(const v8h*)&qrow[quad * 8];
  v8h af1 = *(const v8h*)&qrow[32 + quad * 8];

  // Stage Mk[h] (256 rows x 128 B) -> LDS. chunk c of row r lands at c^(r&7).
  {
    const _Float16* mkrow = &g_MkH[h * (S_ * 64) + tid * 64];
#pragma unroll
    for (int c = 0; c < 8; ++c) {
      v8h v = *(const v8h*)&mkrow[c * 8];
      *(v8h*)(MkS + tid * 128 + ((c ^ (tid & 7)) << 4)) = v;
    }
  }
  __syncthreads();

  // QK^T: per wave 16 tokens x 256 s. B-frags from swizzled LDS.
  v4f acc[16] = {};
#pragma unroll
  for (int st = 0; st < 16; ++st) {
    const int row = st * 16 + l15;
    const int sw  = row & 7;
    v8h b0 = *(const v8h*)(MkS + row * 128 + ((quad ^ sw) << 4));
    v8h b1 = *(const v8h*)(MkS + row * 128 + (((4 + quad) ^ sw) << 4));
    acc[st] = __builtin_amdgcn_mfma_f32_16x16x32_f16(af0, b0, acc[st], 0, 0, 0);
    acc[st] = __builtin_amdgcn_mfma_f32_16x16x32_f16(af1, b1, acc[st], 0, 0, 0);
  }

  // Row softmax: row(token) = quad*4+r, col(s) = st*16+l15. Reduce over l15.
#pragma unroll
  for (int r = 0; r < 4; ++r) {
    float m = -INFINITY;
#pragma unroll
    for (int st = 0; st < 16; ++st) {
      acc[st][r] *= 0.125f;                    // 1/sqrt(64)
      m = fmaxf(m, acc[st][r]);
    }
    m = fmaxf(m, __shfl_xor(m, 1)); m = fmaxf(m, __shfl_xor(m, 2));
    m = fmaxf(m, __shfl_xor(m, 4)); m = fmaxf(m, __shfl_xor(m, 8));
    float ssum = 0.0f;
#pragma unroll
    for (int st = 0; st < 16; ++st) {
      float p = __expf(acc[st][r] - m);
      acc[st][r] = p; ssum += p;
    }
    ssum += __shfl_xor(ssum, 1); ssum += __shfl_xor(ssum, 2);
    ssum += __shfl_xor(ssum, 4); ssum += __shfl_xor(ssum, 8);
    const float inv = 1.0f / ssum;
#pragma unroll
    for (int st = 0; st < 16; ++st) acc[st][r] *= inv;
  }

  // Column partials: col = st*16+l15; sum 4 regs then across quads.
#pragma unroll
  for (int st = 0; st < 16; ++st) {
    float c = acc[st][0] + acc[st][1] + acc[st][2] + acc[st][3];
    c += __shfl_xor(c, 16);
    c += __shfl_xor(c, 32);
    if (quad == 0) csum_sh[wid][st * 16 + l15] = c;
  }
  __syncthreads();   // also fences all MkS reads before Psh overwrite
  g_cpart[((size_t)bh * NTILE_ + tile) * 256 + tid] =
      csum_sh[0][tid] + csum_sh[1][tid] + csum_sh[2][tid] + csum_sh[3][tid];

  // P -> LDS transpose (C-layout -> [t][s]), then v8h-coalesced global store.
#pragma unroll
  for (int st = 0; st < 16; ++st)
#pragma unroll
    for (int r = 0; r < 4; ++r)
      Psh[wid * 16 + quad * 4 + r][st * 16 + l15] = (_Float16)acc[st][r];
  __syncthreads();
  {
    const int r = tid >> 2, q = tid & 3;
    _Float16* prow = &g_P[(((size_t)bh * NTILE_ + tile) * 64 + r) * 256 + q * 64];
#pragma unroll
    for (int j = 0; j < 8; ++j)
      *(v8h*)&prow[j * 8] = *(const v8h*)&Psh[r][q * 64 + j * 8];
  }
}

// ---------------------------------------------------------------------------
// Fold the 64 per-tile partials into 1/(colsum + 1e-6).
// ---------------------------------------------------------------------------
__global__ __launch_bounds__(256) void reduce_colsum() {
  const int bh = blockIdx.x;
  const int s  = threadIdx.x;
  float acc = 0.0f;
#pragma unroll 8
  for (int k = 0; k < NTILE_; ++k)
    acc += g_cpart[((size_t)bh * NTILE_ + k) * 256 + s];
  g_colsum_inv[bh * 256 + s] = 1.0f / (acc + 1e-6f);
}

// ---------------------------------------------------------------------------
// Mv2[b][h][d][s] = MvT[h][d][s] * cinv[b][h][s]  (folds the column
// normalization into the tiny PV B-operand; 1M elems, 512 blocks).
// ---------------------------------------------------------------------------
__global__ __launch_bounds__(256) void scale_mv() {
  const int i8  = blockIdx.x * 256 + threadIdx.x;   // 4*16*64*256/8 = 131072
  const int bhd = i8 >> 5;                          // b*1024 + h*64 + d
  const int sc  = (i8 & 31) * 8;
  const int h   = (bhd >> 6) & 15;
  const int d   = bhd & 63;
  const int bh  = bhd >> 6;                         // b*16 + h
  v8h mv = *(const v8h*)&g_MvT[(h * 64 + d) * 256 + sc];
  const float* cinv = &g_colsum_inv[bh * 256 + sc];
  v8h o;
#pragma unroll
  for (int j = 0; j < 8; ++j) o[j] = (_Float16)((float)mv[j] * cinv[j]);
  *(v8h*)&g_Mv2[(size_t)bhd * 256 + sc] = o;
}

// ---------------------------------------------------------------------------
// Pass 2: pure PV. A-frags straight from g_P (L3-hot, [t][s] layout matches
// the fragment: lane reads 8 consecutive s of its token row). B-frags from
// cinv-scaled g_Mv2 (2 MB, L2-hot). No LDS, no softmax, no recompute.
// Writes fp16 out_pre*512 into g_AH.
// ---------------------------------------------------------------------------
__global__ __launch_bounds__(256) void pv2() {
  const int tid  = threadIdx.x;
  const int bh   = blockIdx.x;
  const int b    = bh >> 4, h = bh & 15;
  const int tile = blockIdx.y;
  const int t0   = tile * 64;
  const int wid  = tid >> 6;
  const int lane = tid & 63;
  const int l15  = lane & 15;
  const int quad = lane >> 4;

  const _Float16* prow =
      &g_P[(((size_t)bh * NTILE_ + tile) * 64 + wid * 16 + l15) * 256];
  v8h af[8];
#pragma unroll
  for (int kc = 0; kc < 8; ++kc)
    af[kc] = *(const v8h*)&prow[kc * 32 + quad * 8];

  const _Float16* mv2 = &g_Mv2[(size_t)bh * 16384];
  v4f oacc[4] = {};
#pragma unroll
  for (int nt = 0; nt < 4; ++nt) {
    const _Float16* mvrow = &mv2[(nt * 16 + l15) * 256];
#pragma unroll
    for (int kc = 0; kc < 8; ++kc) {
      v8h bf = *(const v8h*)&mvrow[kc * 32 + quad * 8];
      oacc[nt] = __builtin_amdgcn_mfma_f32_16x16x32_f16(af[kc], bf, oacc[nt], 0, 0, 0);
    }
  }

  // epilogue: t = t0+wid*16+quad*4+r, d = nt*16+l15; write fp16 out_pre*512
#pragma unroll
  for (int nt = 0; nt < 4; ++nt)
#pragma unroll
    for (int r = 0; r < 4; ++r) {
      const int t = t0 + wid * 16 + quad * 4 + r;
      g_AH[(size_t)(b * T_ + t) * 1024 + h * 64 + nt * 16 + l15] =
          (_Float16)(oacc[nt][r] * 512.0f);
    }
}

// ---------------------------------------------------------------------------
// Pipeline:
//   cvt x->g_AH, Wq->g_WqH, Wo->g_WoH, Mk->g_MkH; transpose Mv->g_MvT
//   gemm_q16: g_AH @ WqH^T -> g_QH (fp16)            [MFMA]
//   attn_p1: QK+softmax ONCE -> g_P (fp16), colsum partials -> g_cpart
//   reduce_colsum -> g_colsum_inv
//   scale_mv: Mv2 = MvT * cinv (folds double-normalization into B operand)
//   pv2: P @ Mv2 -> g_AH (fp16 out_pre*512)           [MFMA, no recompute]
//   gemm_o: g_AH @ WoH^T * (1/512) -> d_out           [MFMA]
// ---------------------------------------------------------------------------
extern "C" void kernel_launch(void* const* d_in, const int* in_sizes, int n_in,
                              void* d_out, int out_size, void* d_ws, size_t ws_size,
                              hipStream_t stream) {
  const float* x  = (const float*)d_in[0];
  const float* Wq = (const float*)d_in[1];
  const float* Wo = (const float*)d_in[2];
  const float* Mk = (const float*)d_in[3];
  const float* Mv = (const float*)d_in[4];
  float* out = (float*)d_out;

  _Float16 *AH, *WqH, *WoH, *MkH;
  (void)hipGetSymbolAddress((void**)&AH,  HIP_SYMBOL(g_AH));
  (void)hipGetSymbolAddress((void**)&WqH, HIP_SYMBOL(g_WqH));
  (void)hipGetSymbolAddress((void**)&WoH, HIP_SYMBOL(g_WoH));
  (void)hipGetSymbolAddress((void**)&MkH, HIP_SYMBOL(g_MkH));

  cvt_h<<<8192, 256, 0, stream>>>(x,  AH);    // 16,777,216 / 2048
  cvt_h<<<512,  256, 0, stream>>>(Wq, WqH);
  cvt_h<<<512,  256, 0, stream>>>(Wo, WoH);
  cvt_h<<<128,  256, 0, stream>>>(Mk, MkH);   //    262,144 / 2048
  transpose_mv<<<1024, 256, 0, stream>>>(Mv);
  gemm_q16<<<dim3(BT_ / 128, DM_ / 128), 256, 0, stream>>>(WqH);
  attn_p1<<<dim3(B_ * H_, NTILE_), 256, 0, stream>>>();
  reduce_colsum<<<dim3(B_ * H_), 256, 0, stream>>>();
  scale_mv<<<512, 256, 0, stream>>>();
  pv2<<<dim3(B_ * H_, NTILE_), 256, 0, stream>>>();
  gemm_o<<<dim3(BT_ / 128, DM_ / 128), 256, 0, stream>>>(WoH, out);
}